// Round 1
// baseline (1351.518 us; speedup 1.0000x reference)
//
#include <hip/hip_runtime.h>
#include <math.h>

#define N_NODES 100000
#define N_EDGES 1600000
#define M_TOT   (N_EDGES + N_NODES)   // edges + self loops = 1,700,000
#define C_DIM   128
#define NEG_SLOPE 0.2f
#define BN_EPS 1e-5f

// ---------------------------------------------------------------------------
// utility kernels
// ---------------------------------------------------------------------------
__global__ void zero_i32(int* __restrict__ p, int n) {
    int i = blockIdx.x * blockDim.x + threadIdx.x;
    if (i < n) p[i] = 0;
}
__global__ void zero_f32(float* __restrict__ p, int n) {
    int i = blockIdx.x * blockDim.x + threadIdx.x;
    if (i < n) p[i] = 0.0f;
}

// ---------------------------------------------------------------------------
// CSR build (sort edges by dst). Edge m in [0,E) comes from edge_index;
// m in [E, M) is the self loop (m - E).
// ---------------------------------------------------------------------------
__global__ void count_deg(const int* __restrict__ ei, int* __restrict__ deg) {
    int m = blockIdx.x * blockDim.x + threadIdx.x;
    if (m >= M_TOT) return;
    int dst = (m < N_EDGES) ? ei[N_EDGES + m] : (m - N_EDGES);
    atomicAdd(&deg[dst], 1);
}

// chunk = 1024 elements per block
__global__ __launch_bounds__(256) void block_sums(const int* __restrict__ deg,
                                                  int* __restrict__ partials) {
    __shared__ int lds[256];
    int base = blockIdx.x * 1024;
    int s = 0;
    for (int i = threadIdx.x; i < 1024; i += 256) {
        int idx = base + i;
        if (idx < N_NODES) s += deg[idx];
    }
    lds[threadIdx.x] = s;
    __syncthreads();
    for (int off = 128; off > 0; off >>= 1) {
        if (threadIdx.x < off) lds[threadIdx.x] += lds[threadIdx.x + off];
        __syncthreads();
    }
    if (threadIdx.x == 0) partials[blockIdx.x] = lds[0];
}

__global__ void scan_partials(int* __restrict__ partials, int nb,
                              int* __restrict__ row_ptr) {
    if (threadIdx.x == 0 && blockIdx.x == 0) {
        int acc = 0;
        for (int i = 0; i < nb; ++i) {
            int t = partials[i];
            partials[i] = acc;
            acc += t;
        }
        row_ptr[N_NODES] = M_TOT;
    }
}

__global__ __launch_bounds__(256) void scan_write(const int* __restrict__ deg,
                                                  const int* __restrict__ partials,
                                                  int* __restrict__ row_ptr,
                                                  int* __restrict__ nextp) {
    __shared__ int lds[256];
    int tid = threadIdx.x;
    int base = blockIdx.x * 1024;
    int i0 = base + tid * 4;
    int d[4];
#pragma unroll
    for (int t = 0; t < 4; ++t)
        d[t] = (i0 + t < N_NODES) ? deg[i0 + t] : 0;
    int tsum = d[0] + d[1] + d[2] + d[3];
    lds[tid] = tsum;
    __syncthreads();
    // inclusive scan over 256 thread sums
    for (int off = 1; off < 256; off <<= 1) {
        int v = (tid >= off) ? lds[tid - off] : 0;
        __syncthreads();
        lds[tid] += v;
        __syncthreads();
    }
    int excl = lds[tid] - tsum;
    int run = partials[blockIdx.x] + excl;
#pragma unroll
    for (int t = 0; t < 4; ++t) {
        if (i0 + t < N_NODES) {
            row_ptr[i0 + t] = run;
            nextp[i0 + t]   = run;
            run += d[t];
        }
    }
}

__global__ void scatter_edges(const int* __restrict__ ei, int* __restrict__ nextp,
                              int* __restrict__ csr_src) {
    int m = blockIdx.x * blockDim.x + threadIdx.x;
    if (m >= M_TOT) return;
    int src, dst;
    if (m < N_EDGES) { src = ei[m]; dst = ei[N_EDGES + m]; }
    else             { src = m - N_EDGES; dst = src; }
    int pos = atomicAdd(&nextp[dst], 1);
    csr_src[pos] = src;
}

// ---------------------------------------------------------------------------
// GEMM: H[N,128] = X[N,128(ld)] @ W[128,128], fused s_src/s_dst epilogue.
// Block = 256 threads, tile = 32 rows x 128 cols, thread tile = 4x4.
// W staged in LDS in two 64-row halves (48 KB total LDS -> 3 blocks/CU).
// ---------------------------------------------------------------------------
__global__ __launch_bounds__(256) void gemm_attn(
    const float* __restrict__ X, int ldx,
    const float* __restrict__ W,
    const float* __restrict__ a_src, const float* __restrict__ a_dst,
    float* __restrict__ H, float* __restrict__ Ssrc, float* __restrict__ Sdst) {
    __shared__ float Ws[64 * 128];   // 32 KB (half of W rows)
    __shared__ float Xs[32 * 128];   // 16 KB
    int tid = threadIdx.x;
    int tx = tid & 31;   // col group
    int ty = tid >> 5;   // row group 0..7
    int j0 = tx * 4;
    int r0 = ty * 4;
    int rbase = blockIdx.x * 32;

    // load X tile (32 rows x 128 cols) as float4
    for (int i = tid; i < 1024; i += 256) {
        int r = i >> 5;
        int c4 = (i & 31) * 4;
        *(float4*)&Xs[r * 128 + c4] =
            *(const float4*)&X[(size_t)(rbase + r) * ldx + c4];
    }

    float acc[4][4] = {};

    for (int kb = 0; kb < 128; kb += 64) {
        __syncthreads();  // protect Ws reuse
        // load 64 rows of W: 8192 floats = 2048 float4
        for (int i = tid * 4; i < 64 * 128; i += 1024) {
            *(float4*)&Ws[i] = *(const float4*)&W[kb * 128 + i];
        }
        __syncthreads();
#pragma unroll 4
        for (int k = 0; k < 64; k += 4) {
            float4 b0 = *(float4*)&Ws[(k + 0) * 128 + j0];
            float4 b1 = *(float4*)&Ws[(k + 1) * 128 + j0];
            float4 b2 = *(float4*)&Ws[(k + 2) * 128 + j0];
            float4 b3 = *(float4*)&Ws[(k + 3) * 128 + j0];
#pragma unroll
            for (int i = 0; i < 4; ++i) {
                float4 a = *(float4*)&Xs[(r0 + i) * 128 + kb + k];
                acc[i][0] = fmaf(a.x, b0.x, fmaf(a.y, b1.x, fmaf(a.z, b2.x, fmaf(a.w, b3.x, acc[i][0]))));
                acc[i][1] = fmaf(a.x, b0.y, fmaf(a.y, b1.y, fmaf(a.z, b2.y, fmaf(a.w, b3.y, acc[i][1]))));
                acc[i][2] = fmaf(a.x, b0.z, fmaf(a.y, b1.z, fmaf(a.z, b2.z, fmaf(a.w, b3.z, acc[i][2]))));
                acc[i][3] = fmaf(a.x, b0.w, fmaf(a.y, b1.w, fmaf(a.z, b2.w, fmaf(a.w, b3.w, acc[i][3]))));
            }
        }
    }

    // epilogue: store H + fused attention logit dot products
    float4 avs = *(const float4*)&a_src[j0];
    float4 avd = *(const float4*)&a_dst[j0];
#pragma unroll
    for (int i = 0; i < 4; ++i) {
        int row = rbase + r0 + i;
        float4 o = make_float4(acc[i][0], acc[i][1], acc[i][2], acc[i][3]);
        *(float4*)&H[(size_t)row * 128 + j0] = o;
        float ps = o.x * avs.x + o.y * avs.y + o.z * avs.z + o.w * avs.w;
        float pd = o.x * avd.x + o.y * avd.y + o.z * avd.z + o.w * avd.w;
        // reduce over the 32 tx lanes (same ty group lives in one half-wave)
#pragma unroll
        for (int off = 1; off < 32; off <<= 1) {
            ps += __shfl_xor(ps, off, 64);
            pd += __shfl_xor(pd, off, 64);
        }
        if (tx == 0) {
            Ssrc[row] = ps;
            Sdst[row] = pd;
        }
    }
}

// ---------------------------------------------------------------------------
// Per-node softmax + weighted aggregation. One wave per node (64 lanes x 2 ch).
// Y = relu(agg/denom + bias)
// ---------------------------------------------------------------------------
__global__ __launch_bounds__(256) void aggregate(
    const float* __restrict__ H, const int* __restrict__ row_ptr,
    const int* __restrict__ csr_src,
    const float* __restrict__ Ssrc, const float* __restrict__ Sdst,
    const float* __restrict__ bias, float* __restrict__ Y) {
    int wave = threadIdx.x >> 6;
    int lane = threadIdx.x & 63;
    int v = blockIdx.x * 4 + wave;
    int start = row_ptr[v];
    int end = row_ptr[v + 1];
    float sdv = Sdst[v];

    // pass 1: segment max of leaky_relu(s_src[u] + s_dst[v])
    float m = -1e30f;
    for (int j = start + lane; j < end; j += 64) {
        float s = Ssrc[csr_src[j]] + sdv;
        s = (s > 0.0f) ? s : NEG_SLOPE * s;
        m = fmaxf(m, s);
    }
#pragma unroll
    for (int off = 32; off >= 1; off >>= 1) m = fmaxf(m, __shfl_xor(m, off, 64));

    // pass 2: weighted sum (denominator accumulated redundantly per lane)
    float denom = 0.0f, ax = 0.0f, ay = 0.0f;
    for (int j = start; j < end; ++j) {
        int u = csr_src[j];
        float s = Ssrc[u] + sdv;
        s = (s > 0.0f) ? s : NEG_SLOPE * s;
        float w = __expf(s - m);
        denom += w;
        float2 hv = *(const float2*)&H[(size_t)u * 128 + lane * 2];
        ax = fmaf(w, hv.x, ax);
        ay = fmaf(w, hv.y, ay);
    }
    float inv = 1.0f / denom;
    float2 b = *(const float2*)&bias[lane * 2];
    float ox = fmaxf(fmaf(ax, inv, b.x), 0.0f);
    float oy = fmaxf(fmaf(ay, inv, b.y), 0.0f);
    *(float2*)&Y[(size_t)v * 128 + lane * 2] = make_float2(ox, oy);
}

// ---------------------------------------------------------------------------
// BatchNorm
// ---------------------------------------------------------------------------
__global__ __launch_bounds__(128) void bn_stats(const float* __restrict__ Y,
                                                float* __restrict__ sums) {
    int c = threadIdx.x;  // 0..127
    float s = 0.0f, q = 0.0f;
    for (int i = blockIdx.x; i < N_NODES; i += gridDim.x) {
        float v = Y[(size_t)i * 128 + c];
        s += v;
        q = fmaf(v, v, q);
    }
    atomicAdd(&sums[c], s);
    atomicAdd(&sums[128 + c], q);
}

__global__ __launch_bounds__(128) void bn_finalize(const float* __restrict__ sums,
                                                   const float* __restrict__ gamma,
                                                   const float* __restrict__ beta,
                                                   float* __restrict__ gb) {
    int c = threadIdx.x;
    const float invN = 1.0f / (float)N_NODES;
    float mu = sums[c] * invN;
    float var = sums[128 + c] * invN - mu * mu;
    float g = gamma[c] * rsqrtf(var + BN_EPS);
    gb[c] = g;
    gb[128 + c] = beta[c] - mu * g;
}

// out is pre-offset to the layer's 128-col slice of the [N,384] output
__global__ __launch_bounds__(256) void bn_apply(const float* __restrict__ Y,
                                                const float* __restrict__ gb,
                                                float* __restrict__ out) {
    int idx = blockIdx.x * blockDim.x + threadIdx.x;  // over N*32 float4 groups
    if (idx >= N_NODES * 32) return;
    int row = idx >> 5;
    int c4 = (idx & 31) * 4;
    float4 v = *(const float4*)&Y[(size_t)row * 128 + c4];
    float4 g = *(const float4*)&gb[c4];
    float4 b = *(const float4*)&gb[128 + c4];
    v.x = fmaf(v.x, g.x, b.x);
    v.y = fmaf(v.y, g.y, b.y);
    v.z = fmaf(v.z, g.z, b.z);
    v.w = fmaf(v.w, g.w, b.w);
    *(float4*)&out[(size_t)row * 384 + c4] = v;
}

// ---------------------------------------------------------------------------
// driver
// ---------------------------------------------------------------------------
extern "C" void kernel_launch(void* const* d_in, const int* in_sizes, int n_in,
                              void* d_out, int out_size, void* d_ws, size_t ws_size,
                              hipStream_t stream) {
    const float* x      = (const float*)d_in[0];
    const int*   ei     = (const int*)d_in[1];   // [2, E] int32
    const float* Wall   = (const float*)d_in[2]; // [3,128,128]
    const float* asrcs  = (const float*)d_in[3]; // [3,128]
    const float* adsts  = (const float*)d_in[4];
    const float* biases = (const float*)d_in[5];
    const float* gammas = (const float*)d_in[6];
    const float* betas  = (const float*)d_in[7];
    float* out = (float*)d_out;

    // workspace layout
    float* H       = (float*)d_ws;             // 12.8M
    float* Y       = H + (size_t)N_NODES * 128; // 12.8M
    float* Ssrc    = Y + (size_t)N_NODES * 128; // 100000
    float* Sdst    = Ssrc + N_NODES;            // 100000
    float* colsums = Sdst + N_NODES;            // 256
    float* gb      = colsums + 256;             // 256
    int* deg       = (int*)(gb + 256);          // 100000
    int* row_ptr   = deg + N_NODES;             // 100001
    int* nextp     = row_ptr + (N_NODES + 1);   // 100000
    int* partials  = nextp + N_NODES;           // 128
    int* csr_src   = partials + 128;            // 1.7M

    const int NB_SCAN = (N_NODES + 1023) / 1024;         // 98
    const int NB_EDGE = (M_TOT + 255) / 256;             // 6641

    // ---- CSR build (once per call; edge list is static input) ----
    zero_i32<<<(N_NODES + 255) / 256, 256, 0, stream>>>(deg, N_NODES);
    count_deg<<<NB_EDGE, 256, 0, stream>>>(ei, deg);
    block_sums<<<NB_SCAN, 256, 0, stream>>>(deg, partials);
    scan_partials<<<1, 64, 0, stream>>>(partials, NB_SCAN, row_ptr);
    scan_write<<<NB_SCAN, 256, 0, stream>>>(deg, partials, row_ptr, nextp);
    scatter_edges<<<NB_EDGE, 256, 0, stream>>>(ei, nextp, csr_src);

    // ---- 3 GAT layers ----
    for (int l = 0; l < 3; ++l) {
        const float* xin = (l == 0) ? x : (out + (size_t)(l - 1) * 128);
        int ldx = (l == 0) ? 128 : 384;
        gemm_attn<<<N_NODES / 32, 256, 0, stream>>>(
            xin, ldx, Wall + (size_t)l * 128 * 128,
            asrcs + l * 128, adsts + l * 128, H, Ssrc, Sdst);
        aggregate<<<N_NODES / 4, 256, 0, stream>>>(
            H, row_ptr, csr_src, Ssrc, Sdst, biases + l * 128, Y);
        zero_f32<<<1, 256, 0, stream>>>(colsums, 256);
        bn_stats<<<1024, 128, 0, stream>>>(Y, colsums);
        bn_finalize<<<1, 128, 0, stream>>>(colsums, gammas + l * 128,
                                           betas + l * 128, gb);
        bn_apply<<<(N_NODES * 32 + 255) / 256, 256, 0, stream>>>(
            Y, gb, out + (size_t)l * 128);
    }
}

// Round 2
// 1138.272 us; speedup vs baseline: 1.1873x; 1.1873x over previous
//
#include <hip/hip_runtime.h>
#include <math.h>

#define N_NODES 100000
#define N_EDGES 1600000
#define M_TOT   (N_EDGES + N_NODES)   // edges + self loops = 1,700,000
#define C_DIM   128
#define NEG_SLOPE 0.2f
#define BN_EPS 1e-5f

// bf16 <-> fp32 helpers (bit-level, RNE on pack)
static __device__ __forceinline__ unsigned short f2bf(float f) {
    unsigned int b = __float_as_uint(f);
    b += 0x7FFFu + ((b >> 16) & 1u);   // round-to-nearest-even
    return (unsigned short)(b >> 16);
}
static __device__ __forceinline__ float bf2f(unsigned short u) {
    return __uint_as_float(((unsigned int)u) << 16);
}

// ---------------------------------------------------------------------------
// utility kernels
// ---------------------------------------------------------------------------
__global__ void zero_i32(int* __restrict__ p, int n) {
    int i = blockIdx.x * blockDim.x + threadIdx.x;
    if (i < n) p[i] = 0;
}
__global__ void zero_f32(float* __restrict__ p, int n) {
    int i = blockIdx.x * blockDim.x + threadIdx.x;
    if (i < n) p[i] = 0.0f;
}

// ---------------------------------------------------------------------------
// CSR build (sort edges by dst). Edge m in [0,E) comes from edge_index;
// m in [E, M) is the self loop (m - E).
// ---------------------------------------------------------------------------
__global__ void count_deg(const int* __restrict__ ei, int* __restrict__ deg) {
    int m = blockIdx.x * blockDim.x + threadIdx.x;
    if (m >= M_TOT) return;
    int dst = (m < N_EDGES) ? ei[N_EDGES + m] : (m - N_EDGES);
    atomicAdd(&deg[dst], 1);
}

// chunk = 1024 elements per block
__global__ __launch_bounds__(256) void block_sums(const int* __restrict__ deg,
                                                  int* __restrict__ partials) {
    __shared__ int lds[256];
    int base = blockIdx.x * 1024;
    int s = 0;
    for (int i = threadIdx.x; i < 1024; i += 256) {
        int idx = base + i;
        if (idx < N_NODES) s += deg[idx];
    }
    lds[threadIdx.x] = s;
    __syncthreads();
    for (int off = 128; off > 0; off >>= 1) {
        if (threadIdx.x < off) lds[threadIdx.x] += lds[threadIdx.x + off];
        __syncthreads();
    }
    if (threadIdx.x == 0) partials[blockIdx.x] = lds[0];
}

__global__ void scan_partials(int* __restrict__ partials, int nb,
                              int* __restrict__ row_ptr) {
    if (threadIdx.x == 0 && blockIdx.x == 0) {
        int acc = 0;
        for (int i = 0; i < nb; ++i) {
            int t = partials[i];
            partials[i] = acc;
            acc += t;
        }
        row_ptr[N_NODES] = M_TOT;
    }
}

__global__ __launch_bounds__(256) void scan_write(const int* __restrict__ deg,
                                                  const int* __restrict__ partials,
                                                  int* __restrict__ row_ptr,
                                                  int* __restrict__ nextp) {
    __shared__ int lds[256];
    int tid = threadIdx.x;
    int base = blockIdx.x * 1024;
    int i0 = base + tid * 4;
    int d[4];
#pragma unroll
    for (int t = 0; t < 4; ++t)
        d[t] = (i0 + t < N_NODES) ? deg[i0 + t] : 0;
    int tsum = d[0] + d[1] + d[2] + d[3];
    lds[tid] = tsum;
    __syncthreads();
    for (int off = 1; off < 256; off <<= 1) {
        int v = (tid >= off) ? lds[tid - off] : 0;
        __syncthreads();
        lds[tid] += v;
        __syncthreads();
    }
    int excl = lds[tid] - tsum;
    int run = partials[blockIdx.x] + excl;
#pragma unroll
    for (int t = 0; t < 4; ++t) {
        if (i0 + t < N_NODES) {
            row_ptr[i0 + t] = run;
            nextp[i0 + t]   = run;
            run += d[t];
        }
    }
}

__global__ void scatter_edges(const int* __restrict__ ei, int* __restrict__ nextp,
                              int* __restrict__ csr_src) {
    int m = blockIdx.x * blockDim.x + threadIdx.x;
    if (m >= M_TOT) return;
    int src, dst;
    if (m < N_EDGES) { src = ei[m]; dst = ei[N_EDGES + m]; }
    else             { src = m - N_EDGES; dst = src; }
    int pos = atomicAdd(&nextp[dst], 1);
    csr_src[pos] = src;
}

// ---------------------------------------------------------------------------
// GEMM: H[N,128] = X[N,128(ld)] @ W[128,128], fused s_src/s_dst epilogue.
// H is stored in bf16 (it only feeds the aggregate gather; threshold is
// bf16-scale). Block = 256 threads, tile = 32 rows x 128 cols, 4x4/thread.
// ---------------------------------------------------------------------------
__global__ __launch_bounds__(256) void gemm_attn(
    const float* __restrict__ X, int ldx,
    const float* __restrict__ W,
    const float* __restrict__ a_src, const float* __restrict__ a_dst,
    unsigned short* __restrict__ Hb, float* __restrict__ Ssrc,
    float* __restrict__ Sdst) {
    __shared__ float Ws[64 * 128];   // 32 KB (half of W rows)
    __shared__ float Xs[32 * 128];   // 16 KB
    int tid = threadIdx.x;
    int tx = tid & 31;   // col group
    int ty = tid >> 5;   // row group 0..7
    int j0 = tx * 4;
    int r0 = ty * 4;
    int rbase = blockIdx.x * 32;

    // load X tile (32 rows x 128 cols) as float4
    for (int i = tid; i < 1024; i += 256) {
        int r = i >> 5;
        int c4 = (i & 31) * 4;
        *(float4*)&Xs[r * 128 + c4] =
            *(const float4*)&X[(size_t)(rbase + r) * ldx + c4];
    }

    float acc[4][4] = {};

    for (int kb = 0; kb < 128; kb += 64) {
        __syncthreads();  // protect Ws reuse
        for (int i = tid * 4; i < 64 * 128; i += 1024) {
            *(float4*)&Ws[i] = *(const float4*)&W[kb * 128 + i];
        }
        __syncthreads();
#pragma unroll 4
        for (int k = 0; k < 64; k += 4) {
            float4 b0 = *(float4*)&Ws[(k + 0) * 128 + j0];
            float4 b1 = *(float4*)&Ws[(k + 1) * 128 + j0];
            float4 b2 = *(float4*)&Ws[(k + 2) * 128 + j0];
            float4 b3 = *(float4*)&Ws[(k + 3) * 128 + j0];
#pragma unroll
            for (int i = 0; i < 4; ++i) {
                float4 a = *(float4*)&Xs[(r0 + i) * 128 + kb + k];
                acc[i][0] = fmaf(a.x, b0.x, fmaf(a.y, b1.x, fmaf(a.z, b2.x, fmaf(a.w, b3.x, acc[i][0]))));
                acc[i][1] = fmaf(a.x, b0.y, fmaf(a.y, b1.y, fmaf(a.z, b2.y, fmaf(a.w, b3.y, acc[i][1]))));
                acc[i][2] = fmaf(a.x, b0.z, fmaf(a.y, b1.z, fmaf(a.z, b2.z, fmaf(a.w, b3.z, acc[i][2]))));
                acc[i][3] = fmaf(a.x, b0.w, fmaf(a.y, b1.w, fmaf(a.z, b2.w, fmaf(a.w, b3.w, acc[i][3]))));
            }
        }
    }

    // epilogue: store H (bf16) + fused attention logit dot products (fp32)
    float4 avs = *(const float4*)&a_src[j0];
    float4 avd = *(const float4*)&a_dst[j0];
#pragma unroll
    for (int i = 0; i < 4; ++i) {
        int row = rbase + r0 + i;
        float4 o = make_float4(acc[i][0], acc[i][1], acc[i][2], acc[i][3]);
        ushort4 ob;
        ob.x = f2bf(o.x); ob.y = f2bf(o.y); ob.z = f2bf(o.z); ob.w = f2bf(o.w);
        *(ushort4*)&Hb[(size_t)row * 128 + j0] = ob;
        float ps = o.x * avs.x + o.y * avs.y + o.z * avs.z + o.w * avs.w;
        float pd = o.x * avd.x + o.y * avd.y + o.z * avd.z + o.w * avd.w;
#pragma unroll
        for (int off = 1; off < 32; off <<= 1) {
            ps += __shfl_xor(ps, off, 64);
            pd += __shfl_xor(pd, off, 64);
        }
        if (tx == 0) {
            Ssrc[row] = ps;
            Sdst[row] = pd;
        }
    }
}

// ---------------------------------------------------------------------------
// Per-node softmax + weighted aggregation. One wave per node (64 lanes x 2 ch).
// H gathered in bf16 (256 B/row), accumulation in fp32.
// Y = relu(agg/denom + bias)
// ---------------------------------------------------------------------------
__global__ __launch_bounds__(256) void aggregate(
    const unsigned short* __restrict__ Hb, const int* __restrict__ row_ptr,
    const int* __restrict__ csr_src,
    const float* __restrict__ Ssrc, const float* __restrict__ Sdst,
    const float* __restrict__ bias, float* __restrict__ Y) {
    int wave = threadIdx.x >> 6;
    int lane = threadIdx.x & 63;
    int v = blockIdx.x * 4 + wave;
    int start = row_ptr[v];
    int end = row_ptr[v + 1];
    float sdv = Sdst[v];

    // pass 1: segment max of leaky_relu(s_src[u] + s_dst[v])
    float m = -1e30f;
    for (int j = start + lane; j < end; j += 64) {
        float s = Ssrc[csr_src[j]] + sdv;
        s = (s > 0.0f) ? s : NEG_SLOPE * s;
        m = fmaxf(m, s);
    }
#pragma unroll
    for (int off = 32; off >= 1; off >>= 1) m = fmaxf(m, __shfl_xor(m, off, 64));

    // pass 2: weighted sum, 2-edge unroll for gather ILP
    float denom = 0.0f, ax = 0.0f, ay = 0.0f;
    int j = start;
    for (; j + 1 < end; j += 2) {
        int u0 = csr_src[j];
        int u1 = csr_src[j + 1];
        float s0 = Ssrc[u0] + sdv;
        float s1 = Ssrc[u1] + sdv;
        ushort2 h0 = *(const ushort2*)&Hb[(size_t)u0 * 128 + lane * 2];
        ushort2 h1 = *(const ushort2*)&Hb[(size_t)u1 * 128 + lane * 2];
        s0 = (s0 > 0.0f) ? s0 : NEG_SLOPE * s0;
        s1 = (s1 > 0.0f) ? s1 : NEG_SLOPE * s1;
        float w0 = __expf(s0 - m);
        float w1 = __expf(s1 - m);
        denom += w0 + w1;
        ax = fmaf(w0, bf2f(h0.x), ax);
        ay = fmaf(w0, bf2f(h0.y), ay);
        ax = fmaf(w1, bf2f(h1.x), ax);
        ay = fmaf(w1, bf2f(h1.y), ay);
    }
    if (j < end) {
        int u = csr_src[j];
        float s = Ssrc[u] + sdv;
        s = (s > 0.0f) ? s : NEG_SLOPE * s;
        float w = __expf(s - m);
        denom += w;
        ushort2 hv = *(const ushort2*)&Hb[(size_t)u * 128 + lane * 2];
        ax = fmaf(w, bf2f(hv.x), ax);
        ay = fmaf(w, bf2f(hv.y), ay);
    }
    float inv = 1.0f / denom;
    float2 b = *(const float2*)&bias[lane * 2];
    float ox = fmaxf(fmaf(ax, inv, b.x), 0.0f);
    float oy = fmaxf(fmaf(ay, inv, b.y), 0.0f);
    *(float2*)&Y[(size_t)v * 128 + lane * 2] = make_float2(ox, oy);
}

// ---------------------------------------------------------------------------
// BatchNorm
// ---------------------------------------------------------------------------
__global__ __launch_bounds__(128) void bn_stats(const float* __restrict__ Y,
                                                float* __restrict__ sums) {
    int c = threadIdx.x;  // 0..127
    float s = 0.0f, q = 0.0f;
    for (int i = blockIdx.x; i < N_NODES; i += gridDim.x) {
        float v = Y[(size_t)i * 128 + c];
        s += v;
        q = fmaf(v, v, q);
    }
    atomicAdd(&sums[c], s);
    atomicAdd(&sums[128 + c], q);
}

__global__ __launch_bounds__(128) void bn_finalize(const float* __restrict__ sums,
                                                   const float* __restrict__ gamma,
                                                   const float* __restrict__ beta,
                                                   float* __restrict__ gb) {
    int c = threadIdx.x;
    const float invN = 1.0f / (float)N_NODES;
    float mu = sums[c] * invN;
    float var = sums[128 + c] * invN - mu * mu;
    float g = gamma[c] * rsqrtf(var + BN_EPS);
    gb[c] = g;
    gb[128 + c] = beta[c] - mu * g;
}

// out is pre-offset to the layer's 128-col slice of the [N,384] output
__global__ __launch_bounds__(256) void bn_apply(const float* __restrict__ Y,
                                                const float* __restrict__ gb,
                                                float* __restrict__ out) {
    int idx = blockIdx.x * blockDim.x + threadIdx.x;  // over N*32 float4 groups
    if (idx >= N_NODES * 32) return;
    int row = idx >> 5;
    int c4 = (idx & 31) * 4;
    float4 v = *(const float4*)&Y[(size_t)row * 128 + c4];
    float4 g = *(const float4*)&gb[c4];
    float4 b = *(const float4*)&gb[128 + c4];
    v.x = fmaf(v.x, g.x, b.x);
    v.y = fmaf(v.y, g.y, b.y);
    v.z = fmaf(v.z, g.z, b.z);
    v.w = fmaf(v.w, g.w, b.w);
    *(float4*)&out[(size_t)row * 384 + c4] = v;
}

// ---------------------------------------------------------------------------
// driver
// ---------------------------------------------------------------------------
extern "C" void kernel_launch(void* const* d_in, const int* in_sizes, int n_in,
                              void* d_out, int out_size, void* d_ws, size_t ws_size,
                              hipStream_t stream) {
    const float* x      = (const float*)d_in[0];
    const int*   ei     = (const int*)d_in[1];   // [2, E] int32
    const float* Wall   = (const float*)d_in[2]; // [3,128,128]
    const float* asrcs  = (const float*)d_in[3]; // [3,128]
    const float* adsts  = (const float*)d_in[4];
    const float* biases = (const float*)d_in[5];
    const float* gammas = (const float*)d_in[6];
    const float* betas  = (const float*)d_in[7];
    float* out = (float*)d_out;

    // workspace layout
    unsigned short* Hb = (unsigned short*)d_ws;              // N*128 bf16 = 25.6MB
    float* Y       = (float*)(Hb + (size_t)N_NODES * 128);   // N*128 fp32
    float* Ssrc    = Y + (size_t)N_NODES * 128;              // 100000
    float* Sdst    = Ssrc + N_NODES;                         // 100000
    float* colsums = Sdst + N_NODES;                         // 256
    float* gb      = colsums + 256;                          // 256
    int* deg       = (int*)(gb + 256);                       // 100000
    int* row_ptr   = deg + N_NODES;                          // 100001
    int* nextp     = row_ptr + (N_NODES + 1);                // 100000
    int* partials  = nextp + N_NODES;                        // 128
    int* csr_src   = partials + 128;                         // 1.7M

    const int NB_SCAN = (N_NODES + 1023) / 1024;             // 98
    const int NB_EDGE = (M_TOT + 255) / 256;                 // 6641

    // ---- CSR build (once per call; edge list is static input) ----
    zero_i32<<<(N_NODES + 255) / 256, 256, 0, stream>>>(deg, N_NODES);
    count_deg<<<NB_EDGE, 256, 0, stream>>>(ei, deg);
    block_sums<<<NB_SCAN, 256, 0, stream>>>(deg, partials);
    scan_partials<<<1, 64, 0, stream>>>(partials, NB_SCAN, row_ptr);
    scan_write<<<NB_SCAN, 256, 0, stream>>>(deg, partials, row_ptr, nextp);
    scatter_edges<<<NB_EDGE, 256, 0, stream>>>(ei, nextp, csr_src);

    // ---- 3 GAT layers ----
    for (int l = 0; l < 3; ++l) {
        const float* xin = (l == 0) ? x : (out + (size_t)(l - 1) * 128);
        int ldx = (l == 0) ? 128 : 384;
        gemm_attn<<<N_NODES / 32, 256, 0, stream>>>(
            xin, ldx, Wall + (size_t)l * 128 * 128,
            asrcs + l * 128, adsts + l * 128, Hb, Ssrc, Sdst);
        aggregate<<<N_NODES / 4, 256, 0, stream>>>(
            Hb, row_ptr, csr_src, Ssrc, Sdst, biases + l * 128, Y);
        zero_f32<<<1, 256, 0, stream>>>(colsums, 256);
        bn_stats<<<1024, 128, 0, stream>>>(Y, colsums);
        bn_finalize<<<1, 128, 0, stream>>>(colsums, gammas + l * 128,
                                           betas + l * 128, gb);
        bn_apply<<<(N_NODES * 32 + 255) / 256, 256, 0, stream>>>(
            Y, gb, out + (size_t)l * 128);
    }
}

// Round 3
// 1070.166 us; speedup vs baseline: 1.2629x; 1.0636x over previous
//
#include <hip/hip_runtime.h>
#include <math.h>

#define N_NODES 100000
#define N_EDGES 1600000
#define M_TOT   (N_EDGES + N_NODES)   // edges + self loops = 1,700,000
#define C_DIM   128
#define NEG_SLOPE 0.2f
#define BN_EPS 1e-5f

#define NBUCK 8
#define BUCK_NODES 12500              // nodes per bucket (100000/8)
#define BUCK_CAP 240000               // mean 212500, sigma ~431 -> safe

// bf16 <-> fp32 helpers (bit-level, RNE on pack)
static __device__ __forceinline__ unsigned short f2bf(float f) {
    unsigned int b = __float_as_uint(f);
    b += 0x7FFFu + ((b >> 16) & 1u);
    return (unsigned short)(b >> 16);
}
static __device__ __forceinline__ float bf2f(unsigned short u) {
    return __uint_as_float(((unsigned int)u) << 16);
}

// ---------------------------------------------------------------------------
// utility kernels
// ---------------------------------------------------------------------------
__global__ void zero_i32(int* __restrict__ p, int n) {
    int i = blockIdx.x * blockDim.x + threadIdx.x;
    if (i < n) p[i] = 0;
}
__global__ void zero_f32(float* __restrict__ p, int n) {
    int i = blockIdx.x * blockDim.x + threadIdx.x;
    if (i < n) p[i] = 0.0f;
}

// ---------------------------------------------------------------------------
// CSR build, XCD-partitioned bucket sort.
// Pass A: bucket edges by dst/12500 with LDS-aggregated span reservation ->
//         coalesced ~256B write runs.
// Pass B/C: bucket p handled by blocks with blockIdx%8==p (round-robin XCD
//         heuristic) -> deg/nextp/csr regions stay in ONE XCD's L2.
// ---------------------------------------------------------------------------
__global__ __launch_bounds__(256) void bucket_edges(const int* __restrict__ ei,
                                                    int* __restrict__ bucket_next,
                                                    int2* __restrict__ buckets) {
    __shared__ int cnt[NBUCK];
    __shared__ int base[NBUCK];
    int tid = threadIdx.x;
    if (tid < NBUCK) cnt[tid] = 0;
    __syncthreads();
    int m = blockIdx.x * 256 + tid;
    int src = 0, dst = 0, p = 0, myoff = 0;
    bool valid = (m < M_TOT);
    if (valid) {
        if (m < N_EDGES) { src = ei[m]; dst = ei[N_EDGES + m]; }
        else             { src = m - N_EDGES; dst = src; }
        p = dst / BUCK_NODES;
        myoff = atomicAdd(&cnt[p], 1);
    }
    __syncthreads();
    if (tid < NBUCK) base[tid] = (cnt[tid] > 0) ? atomicAdd(&bucket_next[tid], cnt[tid]) : 0;
    __syncthreads();
    if (valid) {
        buckets[(size_t)p * BUCK_CAP + base[p] + myoff] = make_int2(src, dst);
    }
}

__global__ __launch_bounds__(256) void count_deg_b(const int2* __restrict__ buckets,
                                                   const int* __restrict__ bucket_next,
                                                   int* __restrict__ deg) {
    int p = blockIdx.x & 7;
    int chunk = blockIdx.x >> 3;
    int len = bucket_next[p];
    const int2* b = buckets + (size_t)p * BUCK_CAP;
    int stride = (gridDim.x >> 3) * 256;
    for (int i = chunk * 256 + threadIdx.x; i < len; i += stride) {
        atomicAdd(&deg[b[i].y], 1);
    }
}

__global__ __launch_bounds__(256) void scatter_b(const int2* __restrict__ buckets,
                                                 const int* __restrict__ bucket_next,
                                                 int* __restrict__ nextp,
                                                 int* __restrict__ csr_src) {
    int p = blockIdx.x & 7;
    int chunk = blockIdx.x >> 3;
    int len = bucket_next[p];
    const int2* b = buckets + (size_t)p * BUCK_CAP;
    int stride = (gridDim.x >> 3) * 256;
    for (int i = chunk * 256 + threadIdx.x; i < len; i += stride) {
        int2 e = b[i];
        int pos = atomicAdd(&nextp[e.y], 1);
        csr_src[pos] = e.x;
    }
}

// ---------------------------------------------------------------------------
// prefix scan over deg -> row_ptr / nextp
// ---------------------------------------------------------------------------
__global__ __launch_bounds__(256) void block_sums(const int* __restrict__ deg,
                                                  int* __restrict__ partials) {
    __shared__ int lds[256];
    int base = blockIdx.x * 1024;
    int s = 0;
    for (int i = threadIdx.x; i < 1024; i += 256) {
        int idx = base + i;
        if (idx < N_NODES) s += deg[idx];
    }
    lds[threadIdx.x] = s;
    __syncthreads();
    for (int off = 128; off > 0; off >>= 1) {
        if (threadIdx.x < off) lds[threadIdx.x] += lds[threadIdx.x + off];
        __syncthreads();
    }
    if (threadIdx.x == 0) partials[blockIdx.x] = lds[0];
}

__global__ void scan_partials(int* __restrict__ partials, int nb,
                              int* __restrict__ row_ptr) {
    if (threadIdx.x == 0 && blockIdx.x == 0) {
        int acc = 0;
        for (int i = 0; i < nb; ++i) {
            int t = partials[i];
            partials[i] = acc;
            acc += t;
        }
        row_ptr[N_NODES] = M_TOT;
    }
}

__global__ __launch_bounds__(256) void scan_write(const int* __restrict__ deg,
                                                  const int* __restrict__ partials,
                                                  int* __restrict__ row_ptr,
                                                  int* __restrict__ nextp) {
    __shared__ int lds[256];
    int tid = threadIdx.x;
    int base = blockIdx.x * 1024;
    int i0 = base + tid * 4;
    int d[4];
#pragma unroll
    for (int t = 0; t < 4; ++t)
        d[t] = (i0 + t < N_NODES) ? deg[i0 + t] : 0;
    int tsum = d[0] + d[1] + d[2] + d[3];
    lds[tid] = tsum;
    __syncthreads();
    for (int off = 1; off < 256; off <<= 1) {
        int v = (tid >= off) ? lds[tid - off] : 0;
        __syncthreads();
        lds[tid] += v;
        __syncthreads();
    }
    int excl = lds[tid] - tsum;
    int run = partials[blockIdx.x] + excl;
#pragma unroll
    for (int t = 0; t < 4; ++t) {
        if (i0 + t < N_NODES) {
            row_ptr[i0 + t] = run;
            nextp[i0 + t]   = run;
            run += d[t];
        }
    }
}

// ---------------------------------------------------------------------------
// GEMM: H[N,128] = X[N,128(ld)] @ W[128,128], fused s_src/s_dst epilogue.
// H stored in bf16. Block = 256 threads, tile 32 rows x 128 cols, 4x4/thread.
// ---------------------------------------------------------------------------
__global__ __launch_bounds__(256) void gemm_attn(
    const float* __restrict__ X, int ldx,
    const float* __restrict__ W,
    const float* __restrict__ a_src, const float* __restrict__ a_dst,
    unsigned short* __restrict__ Hb, float* __restrict__ Ssrc,
    float* __restrict__ Sdst) {
    __shared__ float Ws[64 * 128];   // 32 KB (half of W rows)
    __shared__ float Xs[32 * 128];   // 16 KB
    int tid = threadIdx.x;
    int tx = tid & 31;
    int ty = tid >> 5;
    int j0 = tx * 4;
    int r0 = ty * 4;
    int rbase = blockIdx.x * 32;

    for (int i = tid; i < 1024; i += 256) {
        int r = i >> 5;
        int c4 = (i & 31) * 4;
        *(float4*)&Xs[r * 128 + c4] =
            *(const float4*)&X[(size_t)(rbase + r) * ldx + c4];
    }

    float acc[4][4] = {};

    for (int kb = 0; kb < 128; kb += 64) {
        __syncthreads();
        for (int i = tid * 4; i < 64 * 128; i += 1024) {
            *(float4*)&Ws[i] = *(const float4*)&W[kb * 128 + i];
        }
        __syncthreads();
#pragma unroll 4
        for (int k = 0; k < 64; k += 4) {
            float4 b0 = *(float4*)&Ws[(k + 0) * 128 + j0];
            float4 b1 = *(float4*)&Ws[(k + 1) * 128 + j0];
            float4 b2 = *(float4*)&Ws[(k + 2) * 128 + j0];
            float4 b3 = *(float4*)&Ws[(k + 3) * 128 + j0];
#pragma unroll
            for (int i = 0; i < 4; ++i) {
                float4 a = *(float4*)&Xs[(r0 + i) * 128 + kb + k];
                acc[i][0] = fmaf(a.x, b0.x, fmaf(a.y, b1.x, fmaf(a.z, b2.x, fmaf(a.w, b3.x, acc[i][0]))));
                acc[i][1] = fmaf(a.x, b0.y, fmaf(a.y, b1.y, fmaf(a.z, b2.y, fmaf(a.w, b3.y, acc[i][1]))));
                acc[i][2] = fmaf(a.x, b0.z, fmaf(a.y, b1.z, fmaf(a.z, b2.z, fmaf(a.w, b3.z, acc[i][2]))));
                acc[i][3] = fmaf(a.x, b0.w, fmaf(a.y, b1.w, fmaf(a.z, b2.w, fmaf(a.w, b3.w, acc[i][3]))));
            }
        }
    }

    float4 avs = *(const float4*)&a_src[j0];
    float4 avd = *(const float4*)&a_dst[j0];
#pragma unroll
    for (int i = 0; i < 4; ++i) {
        int row = rbase + r0 + i;
        float4 o = make_float4(acc[i][0], acc[i][1], acc[i][2], acc[i][3]);
        ushort4 ob;
        ob.x = f2bf(o.x); ob.y = f2bf(o.y); ob.z = f2bf(o.z); ob.w = f2bf(o.w);
        *(ushort4*)&Hb[(size_t)row * 128 + j0] = ob;
        float ps = o.x * avs.x + o.y * avs.y + o.z * avs.z + o.w * avs.w;
        float pd = o.x * avd.x + o.y * avd.y + o.z * avd.z + o.w * avd.w;
#pragma unroll
        for (int off = 1; off < 32; off <<= 1) {
            ps += __shfl_xor(ps, off, 64);
            pd += __shfl_xor(pd, off, 64);
        }
        if (tx == 0) {
            Ssrc[row] = ps;
            Sdst[row] = pd;
        }
    }
}

// ---------------------------------------------------------------------------
// Per-node softmax + weighted aggregation. One wave per node (64 lanes x 2 ch).
// ---------------------------------------------------------------------------
__global__ __launch_bounds__(256) void aggregate(
    const unsigned short* __restrict__ Hb, const int* __restrict__ row_ptr,
    const int* __restrict__ csr_src,
    const float* __restrict__ Ssrc, const float* __restrict__ Sdst,
    const float* __restrict__ bias, float* __restrict__ Y) {
    int wave = threadIdx.x >> 6;
    int lane = threadIdx.x & 63;
    int v = blockIdx.x * 4 + wave;
    int start = row_ptr[v];
    int end = row_ptr[v + 1];
    float sdv = Sdst[v];

    // pass 1: segment max of leaky_relu(s_src[u] + s_dst[v])
    float m = -1e30f;
    for (int j = start + lane; j < end; j += 64) {
        float s = Ssrc[csr_src[j]] + sdv;
        s = (s > 0.0f) ? s : NEG_SLOPE * s;
        m = fmaxf(m, s);
    }
#pragma unroll
    for (int off = 32; off >= 1; off >>= 1) m = fmaxf(m, __shfl_xor(m, off, 64));

    // pass 2: weighted sum, 4-edge unroll for gather MLP
    float denom = 0.0f, ax = 0.0f, ay = 0.0f;
    int j = start;
    int n4 = start + ((end - start) & ~3);
    for (; j < n4; j += 4) {
        int u0 = csr_src[j];
        int u1 = csr_src[j + 1];
        int u2 = csr_src[j + 2];
        int u3 = csr_src[j + 3];
        float s0 = Ssrc[u0] + sdv;
        float s1 = Ssrc[u1] + sdv;
        float s2 = Ssrc[u2] + sdv;
        float s3 = Ssrc[u3] + sdv;
        ushort2 h0 = *(const ushort2*)&Hb[(size_t)u0 * 128 + lane * 2];
        ushort2 h1 = *(const ushort2*)&Hb[(size_t)u1 * 128 + lane * 2];
        ushort2 h2 = *(const ushort2*)&Hb[(size_t)u2 * 128 + lane * 2];
        ushort2 h3 = *(const ushort2*)&Hb[(size_t)u3 * 128 + lane * 2];
        s0 = (s0 > 0.0f) ? s0 : NEG_SLOPE * s0;
        s1 = (s1 > 0.0f) ? s1 : NEG_SLOPE * s1;
        s2 = (s2 > 0.0f) ? s2 : NEG_SLOPE * s2;
        s3 = (s3 > 0.0f) ? s3 : NEG_SLOPE * s3;
        float w0 = __expf(s0 - m);
        float w1 = __expf(s1 - m);
        float w2 = __expf(s2 - m);
        float w3 = __expf(s3 - m);
        denom += (w0 + w1) + (w2 + w3);
        ax = fmaf(w0, bf2f(h0.x), ax);
        ay = fmaf(w0, bf2f(h0.y), ay);
        ax = fmaf(w1, bf2f(h1.x), ax);
        ay = fmaf(w1, bf2f(h1.y), ay);
        ax = fmaf(w2, bf2f(h2.x), ax);
        ay = fmaf(w2, bf2f(h2.y), ay);
        ax = fmaf(w3, bf2f(h3.x), ax);
        ay = fmaf(w3, bf2f(h3.y), ay);
    }
    for (; j < end; ++j) {
        int u = csr_src[j];
        float s = Ssrc[u] + sdv;
        s = (s > 0.0f) ? s : NEG_SLOPE * s;
        float w = __expf(s - m);
        denom += w;
        ushort2 hv = *(const ushort2*)&Hb[(size_t)u * 128 + lane * 2];
        ax = fmaf(w, bf2f(hv.x), ax);
        ay = fmaf(w, bf2f(hv.y), ay);
    }
    float inv = 1.0f / denom;
    float2 b = *(const float2*)&bias[lane * 2];
    float ox = fmaxf(fmaf(ax, inv, b.x), 0.0f);
    float oy = fmaxf(fmaf(ay, inv, b.y), 0.0f);
    *(float2*)&Y[(size_t)v * 128 + lane * 2] = make_float2(ox, oy);
}

// ---------------------------------------------------------------------------
// BatchNorm
// ---------------------------------------------------------------------------
__global__ __launch_bounds__(128) void bn_stats(const float* __restrict__ Y,
                                                float* __restrict__ sums) {
    int c = threadIdx.x;
    float s = 0.0f, q = 0.0f;
    for (int i = blockIdx.x; i < N_NODES; i += gridDim.x) {
        float v = Y[(size_t)i * 128 + c];
        s += v;
        q = fmaf(v, v, q);
    }
    atomicAdd(&sums[c], s);
    atomicAdd(&sums[128 + c], q);
}

__global__ __launch_bounds__(128) void bn_finalize(const float* __restrict__ sums,
                                                   const float* __restrict__ gamma,
                                                   const float* __restrict__ beta,
                                                   float* __restrict__ gb) {
    int c = threadIdx.x;
    const float invN = 1.0f / (float)N_NODES;
    float mu = sums[c] * invN;
    float var = sums[128 + c] * invN - mu * mu;
    float g = gamma[c] * rsqrtf(var + BN_EPS);
    gb[c] = g;
    gb[128 + c] = beta[c] - mu * g;
}

__global__ __launch_bounds__(256) void bn_apply(const float* __restrict__ Y,
                                                const float* __restrict__ gb,
                                                float* __restrict__ out) {
    int idx = blockIdx.x * blockDim.x + threadIdx.x;
    if (idx >= N_NODES * 32) return;
    int row = idx >> 5;
    int c4 = (idx & 31) * 4;
    float4 v = *(const float4*)&Y[(size_t)row * 128 + c4];
    float4 g = *(const float4*)&gb[c4];
    float4 b = *(const float4*)&gb[128 + c4];
    v.x = fmaf(v.x, g.x, b.x);
    v.y = fmaf(v.y, g.y, b.y);
    v.z = fmaf(v.z, g.z, b.z);
    v.w = fmaf(v.w, g.w, b.w);
    *(float4*)&out[(size_t)row * 384 + c4] = v;
}

// ---------------------------------------------------------------------------
// driver
// ---------------------------------------------------------------------------
extern "C" void kernel_launch(void* const* d_in, const int* in_sizes, int n_in,
                              void* d_out, int out_size, void* d_ws, size_t ws_size,
                              hipStream_t stream) {
    const float* x      = (const float*)d_in[0];
    const int*   ei     = (const int*)d_in[1];   // [2, E] int32
    const float* Wall   = (const float*)d_in[2];
    const float* asrcs  = (const float*)d_in[3];
    const float* adsts  = (const float*)d_in[4];
    const float* biases = (const float*)d_in[5];
    const float* gammas = (const float*)d_in[6];
    const float* betas  = (const float*)d_in[7];
    float* out = (float*)d_out;

    // workspace layout
    unsigned short* Hb = (unsigned short*)d_ws;              // N*128 bf16
    float* Y       = (float*)(Hb + (size_t)N_NODES * 128);   // N*128 fp32
    float* Ssrc    = Y + (size_t)N_NODES * 128;
    float* Sdst    = Ssrc + N_NODES;
    float* colsums = Sdst + N_NODES;
    float* gb      = colsums + 256;
    int* deg       = (int*)(gb + 256);                       // 100000
    int* bucket_next = deg + N_NODES;                        // 8
    int* row_ptr   = bucket_next + NBUCK;                    // 100001
    int* nextp     = row_ptr + (N_NODES + 1);                // 100000
    int* partials  = nextp + N_NODES;                        // 128
    int* csr_src   = partials + 128;                         // 1.7M
    int2* buckets  = (int2*)(csr_src + M_TOT + 2);           // 8*240000 int2

    const int NB_SCAN = (N_NODES + 1023) / 1024;             // 98
    const int NB_EDGE = (M_TOT + 255) / 256;                 // 6641
    const int NB_PART = 2048;                                // 256 chunks x 8 buckets

    // ---- CSR build (bucketed) ----
    zero_i32<<<(N_NODES + NBUCK + 255) / 256, 256, 0, stream>>>(deg, N_NODES + NBUCK);
    bucket_edges<<<NB_EDGE, 256, 0, stream>>>(ei, bucket_next, buckets);
    count_deg_b<<<NB_PART, 256, 0, stream>>>(buckets, bucket_next, deg);
    block_sums<<<NB_SCAN, 256, 0, stream>>>(deg, partials);
    scan_partials<<<1, 64, 0, stream>>>(partials, NB_SCAN, row_ptr);
    scan_write<<<NB_SCAN, 256, 0, stream>>>(deg, partials, row_ptr, nextp);
    scatter_b<<<NB_PART, 256, 0, stream>>>(buckets, bucket_next, nextp, csr_src);

    // ---- 3 GAT layers ----
    for (int l = 0; l < 3; ++l) {
        const float* xin = (l == 0) ? x : (out + (size_t)(l - 1) * 128);
        int ldx = (l == 0) ? 128 : 384;
        gemm_attn<<<N_NODES / 32, 256, 0, stream>>>(
            xin, ldx, Wall + (size_t)l * 128 * 128,
            asrcs + l * 128, adsts + l * 128, Hb, Ssrc, Sdst);
        aggregate<<<N_NODES / 4, 256, 0, stream>>>(
            Hb, row_ptr, csr_src, Ssrc, Sdst, biases + l * 128, Y);
        zero_f32<<<1, 256, 0, stream>>>(colsums, 256);
        bn_stats<<<1024, 128, 0, stream>>>(Y, colsums);
        bn_finalize<<<1, 128, 0, stream>>>(colsums, gammas + l * 128,
                                           betas + l * 128, gb);
        bn_apply<<<(N_NODES * 32 + 255) / 256, 256, 0, stream>>>(
            Y, gb, out + (size_t)l * 128);
    }
}